// Round 1
// baseline (223.610 us; speedup 1.0000x reference)
//
#include <hip/hip_runtime.h>
#include <hip/hip_bf16.h>

#define KOFF 27
#define C 64
#define BM 64
#define PITCH 72   // shorts; 144 B row pitch -> balanced LDS bank access for b128 reads
#define EPS 1e-5f

typedef __attribute__((ext_vector_type(8))) short short8;
typedef __attribute__((ext_vector_type(4))) float f32x4;

__device__ inline unsigned short f2bf(float x) {
    __hip_bfloat16 h = __float2bfloat16(x);
    unsigned short u;
    __builtin_memcpy(&u, &h, 2);
    return u;
}

// ---- pre-pass 1: feats fp32 -> bf16 ----
__global__ void cvt_feats(const float* __restrict__ in, unsigned short* __restrict__ o, int n4) {
    int i = blockIdx.x * blockDim.x + threadIdx.x;
    if (i < n4) {
        float4 v = ((const float4*)in)[i];
        ushort4 u;
        u.x = f2bf(v.x); u.y = f2bf(v.y); u.z = f2bf(v.z); u.w = f2bf(v.w);
        ((ushort4*)o)[i] = u;
    }
}

// ---- pre-pass 2: W_conv [27][c][d] -> WcT bf16 [27][d][c]; W_lin [k][d] -> WlT bf16 [d][k] ----
__global__ void cvt_w(const float* __restrict__ Wc, const float* __restrict__ Wl,
                      unsigned short* __restrict__ WcT, unsigned short* __restrict__ WlT) {
    int i = blockIdx.x * blockDim.x + threadIdx.x;
    const int NWc = KOFF * 64 * 64;
    if (i < NWc) {
        int k = i >> 12;
        int d = (i >> 6) & 63;
        int c = i & 63;
        WcT[i] = f2bf(Wc[(k << 12) + (c << 6) + d]);
    } else if (i < NWc + 64 * 64) {
        int j = i - NWc;
        int d = j >> 6;
        int kk = j & 63;
        WlT[j] = f2bf(Wl[(kk << 6) + d]);
    }
}

// ---- main fused kernel: sparse conv (gather GEMM) + linear + layernorm ----
__launch_bounds__(256)
__global__ void conv_fused(const unsigned short* __restrict__ feats_bf,
                           const int* __restrict__ nb,
                           const float* __restrict__ b_conv,
                           const float* __restrict__ b_lin,
                           const float* __restrict__ gamma,
                           const float* __restrict__ beta,
                           const unsigned short* __restrict__ WcT,
                           const unsigned short* __restrict__ WlT,
                           float* __restrict__ out, int nvox) {
    __shared__ unsigned short ldsA[BM][PITCH];
    __shared__ int lds_nb[KOFF][BM];

    const int tid = threadIdx.x;
    const int lane = tid & 63;
    const int wave = tid >> 6;
    const int cl = lane & 15;       // column-within-tile / A-row selector
    const int krow = lane >> 4;     // k-group 0..3
    const int wg_row0 = blockIdx.x * BM;

    // stage neighbor indices (transposed [k][row]); guard tail rows
    for (int j = tid; j < BM * KOFF; j += 256) {
        int r = j / KOFF;
        int k = j - r * KOFF;
        int grow = wg_row0 + r;
        lds_nb[k][r] = (grow < nvox) ? nb[(size_t)grow * KOFF + k] : -1;
    }

    // per-lane epilogue constants (col = t*16 + cl fixed for whole kernel)
    float bc[4], bl4[4], g4[4], bt4[4];
#pragma unroll
    for (int t = 0; t < 4; ++t) {
        int col = t * 16 + cl;
        bc[t] = b_conv[col];
        bl4[t] = b_lin[col];
        g4[t] = gamma[col];
        bt4[t] = beta[col];
    }

    f32x4 acc[4];
#pragma unroll
    for (int t = 0; t < 4; ++t) acc[t] = (f32x4){0.f, 0.f, 0.f, 0.f};

    const int arow = wave * 16 + cl;          // A-fragment row for this lane
    const int aoff = krow * 8;                // A-fragment k sub-offset

    for (int ko = 0; ko < KOFF; ++ko) {
        __syncthreads();   // previous iteration's MFMA reads done before overwrite
        // gather-stage 64 rows x 64 ch bf16 into LDS (512 chunks of 16B, 2 per thread)
#pragma unroll
        for (int s = 0; s < 2; ++s) {
            int chunk = tid + s * 256;
            int r = chunk >> 3;
            int part = chunk & 7;
            int idx = lds_nb[ko][r];
            short8 v = (short8){0, 0, 0, 0, 0, 0, 0, 0};
            if (idx >= 0)
                v = *(const short8*)(feats_bf + (size_t)idx * C + part * 8);
            *(short8*)(&ldsA[r][part * 8]) = v;
        }
        __syncthreads();

        const unsigned short* wslice = WcT + (size_t)ko * 4096;
#pragma unroll
        for (int ks = 0; ks < 2; ++ks) {
            short8 a = *(const short8*)(&ldsA[arow][ks * 32 + aoff]);
#pragma unroll
            for (int t = 0; t < 4; ++t) {
                int d = t * 16 + cl;
                short8 b = *(const short8*)(wslice + d * 64 + ks * 32 + aoff);
                acc[t] = __builtin_amdgcn_mfma_f32_16x16x32_bf16(a, b, acc[t], 0, 0, 0);
            }
        }
    }

    // ---- epilogue: +b_conv, round-trip X through LDS as bf16, linear MFMA ----
    __syncthreads();
#pragma unroll
    for (int t = 0; t < 4; ++t) {
#pragma unroll
        for (int i = 0; i < 4; ++i) {
            float x = acc[t][i] + bc[t];
            ldsA[wave * 16 + krow * 4 + i][t * 16 + cl] = f2bf(x);
        }
    }
    __syncthreads();

    f32x4 acc2[4];
#pragma unroll
    for (int t = 0; t < 4; ++t) acc2[t] = (f32x4){0.f, 0.f, 0.f, 0.f};

#pragma unroll
    for (int ks = 0; ks < 2; ++ks) {
        short8 a = *(const short8*)(&ldsA[arow][ks * 32 + aoff]);
#pragma unroll
        for (int t = 0; t < 4; ++t) {
            short8 b = *(const short8*)(WlT + (t * 16 + cl) * 64 + ks * 32 + aoff);
            acc2[t] = __builtin_amdgcn_mfma_f32_16x16x32_bf16(a, b, acc2[t], 0, 0, 0);
        }
    }

    // ---- +b_lin and LayerNorm (reduce across the 16-lane column groups) ----
    float s1[4], s2[4];
#pragma unroll
    for (int i = 0; i < 4; ++i) {
        float a0 = acc2[0][i] + bl4[0];
        float a1 = acc2[1][i] + bl4[1];
        float a2 = acc2[2][i] + bl4[2];
        float a3 = acc2[3][i] + bl4[3];
        acc2[0][i] = a0; acc2[1][i] = a1; acc2[2][i] = a2; acc2[3][i] = a3;
        s1[i] = a0 + a1 + a2 + a3;
        s2[i] = a0 * a0 + a1 * a1 + a2 * a2 + a3 * a3;
    }
#pragma unroll
    for (int m = 1; m < 16; m <<= 1) {
#pragma unroll
        for (int i = 0; i < 4; ++i) {
            s1[i] += __shfl_xor(s1[i], m, 64);
            s2[i] += __shfl_xor(s2[i], m, 64);
        }
    }

#pragma unroll
    for (int i = 0; i < 4; ++i) {
        float mu = s1[i] * (1.f / 64.f);
        float var = s2[i] * (1.f / 64.f) - mu * mu;
        float rs = rsqrtf(var + EPS);
        int grow = wg_row0 + wave * 16 + krow * 4 + i;
        if (grow < nvox) {
#pragma unroll
            for (int t = 0; t < 4; ++t) {
                out[(size_t)grow * 64 + t * 16 + cl] = g4[t] * (acc2[t][i] - mu) * rs + bt4[t];
            }
        }
    }
}

extern "C" void kernel_launch(void* const* d_in, const int* in_sizes, int n_in,
                              void* d_out, int out_size, void* d_ws, size_t ws_size,
                              hipStream_t stream) {
    const float* feats = (const float*)d_in[0];
    const int* nb = (const int*)d_in[1];
    const float* Wc = (const float*)d_in[2];
    const float* b_conv = (const float*)d_in[3];
    const float* Wl = (const float*)d_in[4];
    const float* b_lin = (const float*)d_in[5];
    const float* gamma = (const float*)d_in[6];
    const float* beta = (const float*)d_in[7];
    float* out = (float*)d_out;

    const int nvox = in_sizes[0] / C;

    unsigned short* feats_bf = (unsigned short*)d_ws;
    unsigned short* WcT = feats_bf + (size_t)nvox * C;
    unsigned short* WlT = WcT + KOFF * 64 * 64;

    int n4 = (nvox * C) / 4;
    cvt_feats<<<(n4 + 255) / 256, 256, 0, stream>>>(feats, feats_bf, n4);

    int nw = KOFF * 64 * 64 + 64 * 64;
    cvt_w<<<(nw + 255) / 256, 256, 0, stream>>>(Wc, Wl, WcT, WlT);

    int nblk = (nvox + BM - 1) / BM;
    conv_fused<<<nblk, 256, 0, stream>>>(feats_bf, nb, b_conv, b_lin, gamma, beta,
                                         WcT, WlT, out, nvox);
}

// Round 2
// 138.187 us; speedup vs baseline: 1.6182x; 1.6182x over previous
//
#include <hip/hip_runtime.h>
#include <hip/hip_bf16.h>

#define KOFF 27
#define C 64
#define RPB 128          // rows per block (4 waves x 32 rows)
#define PITCH 72         // shorts; 144 B pitch -> 2-way (free) bank access
#define EPS 1e-5f

typedef __attribute__((ext_vector_type(8))) short short8;
typedef __attribute__((ext_vector_type(4))) float f32x4;

__device__ inline unsigned short f2bf(float x) {
    __hip_bfloat16 h = __float2bfloat16(x);
    unsigned short u;
    __builtin_memcpy(&u, &h, 2);
    return u;
}

// ---- pre-pass 1: feats fp32 -> bf16 ----
__global__ void cvt_feats(const float* __restrict__ in, unsigned short* __restrict__ o, int n4) {
    int i = blockIdx.x * blockDim.x + threadIdx.x;
    if (i < n4) {
        float4 v = ((const float4*)in)[i];
        ushort4 u;
        u.x = f2bf(v.x); u.y = f2bf(v.y); u.z = f2bf(v.z); u.w = f2bf(v.w);
        ((ushort4*)o)[i] = u;
    }
}

// ---- pre-pass 2: transpose+convert weights; also zero the zero-page ----
__global__ void cvt_w(const float* __restrict__ Wc, const float* __restrict__ Wl,
                      unsigned short* __restrict__ WcT, unsigned short* __restrict__ WlT,
                      unsigned short* __restrict__ Z) {
    int i = blockIdx.x * blockDim.x + threadIdx.x;
    const int NWc = KOFF * 4096;
    if (i < NWc) {
        int k = i >> 12;
        int d = (i >> 6) & 63;
        int c = i & 63;
        WcT[i] = f2bf(Wc[(k << 12) + (c << 6) + d]);
    } else if (i < NWc + 4096) {
        int j = i - NWc;
        int d = j >> 6;
        int kk = j & 63;
        WlT[j] = f2bf(Wl[(kk << 6) + d]);
    } else if (i < NWc + 4096 + 128) {
        Z[i - NWc - 4096] = 0;
    }
}

struct SMem {
    union {
        int nb[RPB * KOFF];               // 13824 B, live during k-loop
        unsigned short x[RPB][PITCH];     // 18432 B, live in epilogue
    };
};

// ---- main fused kernel: barrier-free gather-GEMM k-loop + linear + LN ----
__launch_bounds__(256)
__global__ void conv_fused(const unsigned short* __restrict__ feats,
                           const int* __restrict__ nb,
                           const float* __restrict__ b_conv,
                           const float* __restrict__ b_lin,
                           const float* __restrict__ gamma,
                           const float* __restrict__ beta,
                           const unsigned short* __restrict__ WcT,
                           const unsigned short* __restrict__ WlT,
                           const unsigned short* __restrict__ zpage,
                           float* __restrict__ out, int nvox) {
    __shared__ SMem sm;
    const int tid = threadIdx.x;
    const int lane = tid & 63;
    const int wave = tid >> 6;
    const int m = lane & 15;        // A row / B col selector
    const int krow = lane >> 4;     // k sub-group 0..3
    const int coff = krow * 8;      // k sub-offset (shorts)
    const int row0 = blockIdx.x * RPB;

    // stage neighbor indices, flat coalesced (row < nvox  <=>  g < nvox*27)
    {
        const int gbase = row0 * KOFF;
        const int glim = nvox * KOFF;
        for (int j = tid; j < RPB * KOFF; j += 256) {
            int g = gbase + j;
            sm.nb[j] = (g < glim) ? nb[g] : -1;
        }
    }
    __syncthreads();

    const int r0 = wave * 32 + m;   // this lane's A row, row-block 0 (block-local)
    const int r1 = r0 + 16;         // row-block 1

    f32x4 acc0[4], acc1[4];
#pragma unroll
    for (int t = 0; t < 4; ++t) {
        acc0[t] = (f32x4){0.f, 0.f, 0.f, 0.f};
        acc1[t] = (f32x4){0.f, 0.f, 0.f, 0.f};
    }

    auto lda = [&](int idx, int ks) -> short8 {
        const unsigned short* p = (idx >= 0) ? (feats + ((size_t)(unsigned)idx << 6)) : zpage;
        return *(const short8*)(p + ks * 32 + coff);
    };

    // software pipeline: A-fragments depth-1, idx depth-2; B left to scheduler
    int i0n = sm.nb[r0 * KOFF];
    int i1n = sm.nb[r1 * KOFF];
    short8 a00 = lda(i0n, 0), a01 = lda(i0n, 1);
    short8 a10 = lda(i1n, 0), a11 = lda(i1n, 1);
    i0n = sm.nb[r0 * KOFF + 1];
    i1n = sm.nb[r1 * KOFF + 1];

#pragma unroll 3
    for (int ko = 0; ko < KOFF; ++ko) {
        int kn2 = (ko + 2 < KOFF) ? ko + 2 : KOFF - 1;
        int i0f = sm.nb[r0 * KOFF + kn2];
        int i1f = sm.nb[r1 * KOFF + kn2];
        // issue next-ko A gathers (idx loaded two iterations ago -> ready)
        short8 n00 = lda(i0n, 0), n01 = lda(i0n, 1);
        short8 n10 = lda(i1n, 0), n11 = lda(i1n, 1);
        // current-ko B fragments (pure f(ko): scheduler may hoist across iters)
        const unsigned short* w = WcT + (size_t)ko * 4096 + m * 64 + coff;
        short8 b0[4], b1[4];
#pragma unroll
        for (int t = 0; t < 4; ++t) {
            b0[t] = *(const short8*)(w + t * 1024);
            b1[t] = *(const short8*)(w + t * 1024 + 32);
        }
#pragma unroll
        for (int t = 0; t < 4; ++t) {
            acc0[t] = __builtin_amdgcn_mfma_f32_16x16x32_bf16(a00, b0[t], acc0[t], 0, 0, 0);
            acc1[t] = __builtin_amdgcn_mfma_f32_16x16x32_bf16(a10, b0[t], acc1[t], 0, 0, 0);
            acc0[t] = __builtin_amdgcn_mfma_f32_16x16x32_bf16(a01, b1[t], acc0[t], 0, 0, 0);
            acc1[t] = __builtin_amdgcn_mfma_f32_16x16x32_bf16(a11, b1[t], acc1[t], 0, 0, 0);
        }
        a00 = n00; a01 = n01; a10 = n10; a11 = n11;
        i0n = i0f; i1n = i1f;
    }

    // ---- epilogue constants (deferred to keep k-loop VGPR pressure low) ----
    float bc[4], bl[4], g4[4], bt[4];
#pragma unroll
    for (int t = 0; t < 4; ++t) {
        int col = t * 16 + m;
        bc[t] = b_conv[col];
        bl[t] = b_lin[col];
        g4[t] = gamma[col];
        bt[t] = beta[col];
    }

    __syncthreads();   // all waves done with sm.nb before overwriting as sm.x
    // conv-out + b_conv -> bf16 X tile (each wave writes only its own 32 rows)
#pragma unroll
    for (int t = 0; t < 4; ++t) {
#pragma unroll
        for (int i = 0; i < 4; ++i) {
            sm.x[wave * 32 + krow * 4 + i][t * 16 + m] = f2bf(acc0[t][i] + bc[t]);
            sm.x[wave * 32 + 16 + krow * 4 + i][t * 16 + m] = f2bf(acc1[t][i] + bc[t]);
        }
    }
    __syncthreads();

    // ---- linear: X @ W_lin ----
    f32x4 d0[4], d1[4];
#pragma unroll
    for (int t = 0; t < 4; ++t) {
        d0[t] = (f32x4){0.f, 0.f, 0.f, 0.f};
        d1[t] = (f32x4){0.f, 0.f, 0.f, 0.f};
    }
    short8 xa00 = *(const short8*)(&sm.x[wave * 32 + m][coff]);
    short8 xa01 = *(const short8*)(&sm.x[wave * 32 + m][32 + coff]);
    short8 xa10 = *(const short8*)(&sm.x[wave * 32 + 16 + m][coff]);
    short8 xa11 = *(const short8*)(&sm.x[wave * 32 + 16 + m][32 + coff]);
#pragma unroll
    for (int t = 0; t < 4; ++t) {
        short8 wb0 = *(const short8*)(WlT + t * 1024 + m * 64 + coff);
        short8 wb1 = *(const short8*)(WlT + t * 1024 + m * 64 + 32 + coff);
        d0[t] = __builtin_amdgcn_mfma_f32_16x16x32_bf16(xa00, wb0, d0[t], 0, 0, 0);
        d0[t] = __builtin_amdgcn_mfma_f32_16x16x32_bf16(xa01, wb1, d0[t], 0, 0, 0);
        d1[t] = __builtin_amdgcn_mfma_f32_16x16x32_bf16(xa10, wb0, d1[t], 0, 0, 0);
        d1[t] = __builtin_amdgcn_mfma_f32_16x16x32_bf16(xa11, wb1, d1[t], 0, 0, 0);
    }

    // ---- +b_lin and LayerNorm (reduce across 16-lane column groups) ----
#pragma unroll
    for (int rb = 0; rb < 2; ++rb) {
        f32x4* d = rb ? d1 : d0;
        float s1[4], s2[4];
#pragma unroll
        for (int i = 0; i < 4; ++i) {
            float a0 = d[0][i] + bl[0];
            float a1 = d[1][i] + bl[1];
            float a2 = d[2][i] + bl[2];
            float a3 = d[3][i] + bl[3];
            d[0][i] = a0; d[1][i] = a1; d[2][i] = a2; d[3][i] = a3;
            s1[i] = a0 + a1 + a2 + a3;
            s2[i] = a0 * a0 + a1 * a1 + a2 * a2 + a3 * a3;
        }
#pragma unroll
        for (int msk = 1; msk < 16; msk <<= 1) {
#pragma unroll
            for (int i = 0; i < 4; ++i) {
                s1[i] += __shfl_xor(s1[i], msk, 64);
                s2[i] += __shfl_xor(s2[i], msk, 64);
            }
        }
#pragma unroll
        for (int i = 0; i < 4; ++i) {
            float mu = s1[i] * (1.f / 64.f);
            float var = s2[i] * (1.f / 64.f) - mu * mu;
            float rs = rsqrtf(var + EPS);
            int grow = row0 + wave * 32 + rb * 16 + krow * 4 + i;
            if (grow < nvox) {
#pragma unroll
                for (int t = 0; t < 4; ++t) {
                    out[(size_t)grow * 64 + t * 16 + m] = g4[t] * (d[t][i] - mu) * rs + bt[t];
                }
            }
        }
    }
}

extern "C" void kernel_launch(void* const* d_in, const int* in_sizes, int n_in,
                              void* d_out, int out_size, void* d_ws, size_t ws_size,
                              hipStream_t stream) {
    const float* feats = (const float*)d_in[0];
    const int* nb = (const int*)d_in[1];
    const float* Wc = (const float*)d_in[2];
    const float* b_conv = (const float*)d_in[3];
    const float* Wl = (const float*)d_in[4];
    const float* b_lin = (const float*)d_in[5];
    const float* gamma = (const float*)d_in[6];
    const float* beta = (const float*)d_in[7];
    float* out = (float*)d_out;

    const int nvox = in_sizes[0] / C;

    unsigned short* feats_bf = (unsigned short*)d_ws;
    unsigned short* WcT = feats_bf + (size_t)nvox * C;
    unsigned short* WlT = WcT + KOFF * 4096;
    unsigned short* Z = WlT + 4096;

    int n4 = (nvox * C) / 4;
    cvt_feats<<<(n4 + 255) / 256, 256, 0, stream>>>(feats, feats_bf, n4);

    int nw = KOFF * 4096 + 4096 + 128;
    cvt_w<<<(nw + 255) / 256, 256, 0, stream>>>(Wc, Wl, WcT, WlT, Z);

    int nblk = (nvox + RPB - 1) / RPB;
    conv_fused<<<nblk, 256, 0, stream>>>(feats_bf, nb, b_conv, b_lin, gamma, beta,
                                         WcT, WlT, Z, out, nvox);
}